// Round 10
// baseline (118.597 us; speedup 1.0000x reference)
//
#include <hip/hip_runtime.h>

// LengthRegulator, round 10: reordered dense sweep.
// Output space is traversed as [all LIVE rows, concat by batch][all TAIL rows,
// concat by batch] in ONE static grid-stride kernel: live rows do x-gather +
// NT store (dense read+write phase), tail rows do dense zero fill with regular
// stores (pure-write phase at fill rate). No dead iterations (R9's mistake),
// no inter-phase launch gap. g->(batch,p) via 5-step search over 33-entry LDS
// prefix table of mel_len.
// B=32, T=1024, C=384, MAX_LEN=8192. Durations arrive as int32.

#define BB 32
#define TT 1024
#define CC 384
#define MAXLEN 8192
#define OUT0 (BB * MAXLEN * CC)     // 100663296 floats
#define QPR (CC / 4)                // 96 float4 per row
#define GBLK 4096
#define GTHR 256
#define STEP (GBLK * GTHR)          // 1048576
#define TOTALQ (BB * MAXLEN * QPR)  // 25165824

typedef float f32x4 __attribute__((ext_vector_type(4)));

// ---------------- Kernel 1: prep (one block per batch) ----------------
// shuffle-scan cumsum + searchsorted -> idx; mel_len as int (ws) and float (out).
__global__ __launch_bounds__(256) void lr_prep(const int4* __restrict__ dur4,
                                               int* __restrict__ idx,
                                               int* __restrict__ ml_out,
                                               float* __restrict__ mel_out) {
    __shared__ int cum[TT];
    __shared__ int wsum[4];
    const int b = blockIdx.x, t = threadIdx.x, lane = t & 63, w = t >> 6;

    int4 d = dur4[b * (TT / 4) + t];
    int s0 = d.x, s1 = s0 + d.y, s2 = s1 + d.z, s3 = s2 + d.w;
    int v = s3;
    #pragma unroll
    for (int dd = 1; dd < 64; dd <<= 1) {
        int u = __shfl_up(v, dd);
        if (lane >= dd) v += u;
    }
    if (lane == 63) wsum[w] = v;
    __syncthreads();
    int prefix = 0;
    #pragma unroll
    for (int i = 0; i < 4; ++i) prefix += (i < w) ? wsum[i] : 0;
    const int base = prefix + v - s3;          // exclusive prefix for this thread's 4
    cum[4 * t + 0] = base + s0;
    cum[4 * t + 1] = base + s1;
    cum[4 * t + 2] = base + s2;
    cum[4 * t + 3] = base + s3;
    __syncthreads();
    const int ml = cum[TT - 1];
    if (t == 0) { mel_out[b] = (float)ml; ml_out[b] = ml; }

    #pragma unroll
    for (int k = 0; k < MAXLEN / 256; ++k) {   // 32 positions per thread
        int p = t + k * 256;
        int r = -1;
        if (p < ml) {
            int lo = 0, hi = TT;
            while (lo < hi) {                  // lo = count(cum <= p)
                int mid = (lo + hi) >> 1;
                if (cum[mid] <= p) lo = mid + 1; else hi = mid;
            }
            r = (lo < TT - 1) ? lo : (TT - 1);
        }
        idx[b * MAXLEN + p] = r;
    }
}

// ---------------- Kernel 2: reordered dense sweep ----------------
__global__ __launch_bounds__(GTHR) void lr_sweep(const f32x4* __restrict__ x4,
                                                 const int* __restrict__ idx,
                                                 const int* __restrict__ ml,
                                                 f32x4* __restrict__ out4) {
    __shared__ int cumL[BB + 1];   // prefix of live rows per batch
    __shared__ int cumT[BB + 1];   // prefix of tail rows per batch
    __shared__ int mls[BB];
    const int t = threadIdx.x;
    if (t < BB) mls[t] = ml[t];
    __syncthreads();
    if (t == 0) {
        int a = 0, c = 0;
        cumL[0] = 0; cumT[0] = 0;
        for (int b = 0; b < BB; ++b) {
            a += mls[b];
            c += MAXLEN - mls[b];
            cumL[b + 1] = a;
            cumT[b + 1] = c;
        }
    }
    __syncthreads();
    const int L = cumL[BB];                    // total live rows

    unsigned gid = blockIdx.x * GTHR + (unsigned)t;
    #pragma unroll 2
    for (unsigned g = gid; g < TOTALQ; g += STEP) {   // 24 iterations, static
        unsigned r    = g / QPR;               // reordered global row
        unsigned lane = g - r * QPR;
        if ((int)r < L) {
            // live: batch = largest b with cumL[b] <= r
            int lo = 0, hi = BB;
            while (lo + 1 < hi) { int mid = (lo + hi) >> 1; if (cumL[mid] <= (int)r) lo = mid; else hi = mid; }
            const int b = lo;
            const int p = (int)r - cumL[b];
            const int i = idx[b * MAXLEN + p];          // >= 0 guaranteed (p < ml[b])
            f32x4 vv = x4[((size_t)b * TT + (unsigned)i) * QPR + lane];
            __builtin_nontemporal_store(vv, &out4[((size_t)b * MAXLEN + p) * QPR + lane]);
        } else {
            // tail: dense zero fill, regular stores (fill-rate path)
            const int rt = (int)r - L;
            int lo = 0, hi = BB;
            while (lo + 1 < hi) { int mid = (lo + hi) >> 1; if (cumT[mid] <= rt) lo = mid; else hi = mid; }
            const int b = lo;
            const int p = mls[b] + (rt - cumT[b]);
            out4[((size_t)b * MAXLEN + p) * QPR + lane] = (f32x4)0.f;
        }
    }
}

extern "C" void kernel_launch(void* const* d_in, const int* in_sizes, int n_in,
                              void* d_out, int out_size, void* d_ws, size_t ws_size,
                              hipStream_t stream) {
    const float* x   = (const float*)d_in[0];
    const int*   dur = (const int*)d_in[1];   // int64 in reference -> int32 on device
    float* out = (float*)d_out;

    int* idx = (int*)d_ws;                    // B*MAXLEN int32 = 1 MB
    int* ml  = idx + BB * MAXLEN;             // 32 int32

    lr_prep<<<BB, 256, 0, stream>>>((const int4*)dur, idx, ml, out + OUT0);
    lr_sweep<<<GBLK, GTHR, 0, stream>>>((const f32x4*)x, idx, ml, (f32x4*)out);
}

// Round 11
// 97.550 us; speedup vs baseline: 1.2157x; 1.2157x over previous
//
#include <hip/hip_runtime.h>

// LengthRegulator, round 11: dense temporal stream separation.
//   prep   : cumsum + searchsorted -> idx, ml, mel_len (proven R8 kernel).
//   rowmap : compact live rows -> rowmap[r] = b*8192+p (dense), totL.
//   gather : dense sweep over live quads only; NT stores; two-half ILP.
//   fill   : per-batch tail rows only; dense zero fill; REGULAR stores
//            (temporally isolated pure-write phase = harness-fill conditions).
// B=32, T=1024, C=384, MAX_LEN=8192. Durations arrive as int32.

#define BB 32
#define TT 1024
#define CC 384
#define MAXLEN 8192
#define OUT0 (BB * MAXLEN * CC)   // 100663296 floats
#define QPR (CC / 4)              // 96 float4 per row

typedef float f32x4 __attribute__((ext_vector_type(4)));

// ---------------- Kernel 1: prep (one block per batch) ----------------
__global__ __launch_bounds__(256) void lr_prep(const int4* __restrict__ dur4,
                                               int* __restrict__ idx,
                                               int* __restrict__ ml_out,
                                               float* __restrict__ mel_out) {
    __shared__ int cum[TT];
    __shared__ int wsum[4];
    const int b = blockIdx.x, t = threadIdx.x, lane = t & 63, w = t >> 6;

    int4 d = dur4[b * (TT / 4) + t];
    int s0 = d.x, s1 = s0 + d.y, s2 = s1 + d.z, s3 = s2 + d.w;
    int v = s3;
    #pragma unroll
    for (int dd = 1; dd < 64; dd <<= 1) {
        int u = __shfl_up(v, dd);
        if (lane >= dd) v += u;
    }
    if (lane == 63) wsum[w] = v;
    __syncthreads();
    int prefix = 0;
    #pragma unroll
    for (int i = 0; i < 4; ++i) prefix += (i < w) ? wsum[i] : 0;
    const int base = prefix + v - s3;
    cum[4 * t + 0] = base + s0;
    cum[4 * t + 1] = base + s1;
    cum[4 * t + 2] = base + s2;
    cum[4 * t + 3] = base + s3;
    __syncthreads();
    const int ml = cum[TT - 1];
    if (t == 0) { mel_out[b] = (float)ml; ml_out[b] = ml; }

    #pragma unroll
    for (int k = 0; k < MAXLEN / 256; ++k) {
        int p = t + k * 256;
        int r = -1;
        if (p < ml) {
            int lo = 0, hi = TT;
            while (lo < hi) {
                int mid = (lo + hi) >> 1;
                if (cum[mid] <= p) lo = mid + 1; else hi = mid;
            }
            r = (lo < TT - 1) ? lo : (TT - 1);
        }
        idx[b * MAXLEN + p] = r;
    }
}

// ---------------- Kernel 2: rowmap (dense live-row list) ----------------
__global__ __launch_bounds__(256) void lr_rowmap(const int* __restrict__ ml,
                                                 int* __restrict__ rowmap,
                                                 int* __restrict__ totL) {
    __shared__ int mls[BB];
    __shared__ int base_s;
    const int b = blockIdx.x, t = threadIdx.x;
    if (t < BB) mls[t] = ml[t];
    __syncthreads();
    if (t == 0) {
        int a = 0;
        for (int i = 0; i < b; ++i) a += mls[i];
        base_s = a;
        if (b == 0) {
            int tot = 0;
            for (int i = 0; i < BB; ++i) tot += mls[i];
            totL[0] = tot;
        }
    }
    __syncthreads();
    const int base = base_s, m = mls[b];
    for (int p = t; p < m; p += 256) rowmap[base + p] = (b << 13) | p;
}

// ---------------- Kernel 3: gather (dense live quads, NT stores) ----------------
__global__ __launch_bounds__(256) void lr_gather(const f32x4* __restrict__ x4,
                                                 const int* __restrict__ idx,
                                                 const int* __restrict__ rowmap,
                                                 const int* __restrict__ totLp,
                                                 f32x4* __restrict__ out4) {
    const unsigned totQ = (unsigned)totLp[0] * QPR;   // uniform scalar load
    const unsigned HALF = totQ >> 1;                  // totQ = totL*96, always even
    const unsigned stride = gridDim.x * blockDim.x;
    for (unsigned q = blockIdx.x * blockDim.x + threadIdx.x; q < HALF; q += stride) {
        const unsigned q2 = q + HALF;
        unsigned r1 = q / QPR,  ln1 = q  - r1 * QPR;
        unsigned r2 = q2 / QPR, ln2 = q2 - r2 * QPR;
        int rm1 = rowmap[r1];              // = b*8192+p = output row = idx index
        int rm2 = rowmap[r2];
        int i1 = idx[rm1];
        int i2 = idx[rm2];
        f32x4 v1 = x4[((size_t)(rm1 >> 13) * TT + (unsigned)i1) * QPR + ln1];
        f32x4 v2 = x4[((size_t)(rm2 >> 13) * TT + (unsigned)i2) * QPR + ln2];
        __builtin_nontemporal_store(v1, &out4[(size_t)rm1 * QPR + ln1]);
        __builtin_nontemporal_store(v2, &out4[(size_t)rm2 * QPR + ln2]);
    }
}

// ---------------- Kernel 4: fill (dense tail rows, regular stores) ----------------
// grid (128 chunks x 32 batches), chunk = 64 rows; blocks fully inside the live
// region exit immediately; boundary chunk predicated per row.
__global__ __launch_bounds__(256) void lr_fill(const int* __restrict__ ml,
                                               f32x4* __restrict__ out4) {
    const int b = blockIdx.y;
    const int m = ml[b];
    const int r0 = blockIdx.x * 64;
    if (r0 + 64 <= m) return;                 // fully live -> nothing to fill
    const int t = threadIdx.x;
    f32x4* ob = out4 + (size_t)b * MAXLEN * QPR;
    #pragma unroll 4
    for (int k = 0; k < 64 * QPR / 256; ++k) {   // 24 iterations
        int q = t + k * 256;
        int row = r0 + q / QPR;
        if (row >= m) ob[(size_t)row * QPR + (q - (q / QPR) * QPR)] = (f32x4)0.f;
    }
}

extern "C" void kernel_launch(void* const* d_in, const int* in_sizes, int n_in,
                              void* d_out, int out_size, void* d_ws, size_t ws_size,
                              hipStream_t stream) {
    const float* x   = (const float*)d_in[0];
    const int*   dur = (const int*)d_in[1];   // int64 in reference -> int32 on device
    float* out = (float*)d_out;

    // ws: idx[262144] | rowmap[262144] | ml[32] | totL[1]  (~2.1 MB)
    int* idx    = (int*)d_ws;
    int* rowmap = idx + BB * MAXLEN;
    int* ml     = rowmap + BB * MAXLEN;
    int* totL   = ml + BB;

    lr_prep<<<BB, 256, 0, stream>>>((const int4*)dur, idx, ml, out + OUT0);
    lr_rowmap<<<BB, 256, 0, stream>>>(ml, rowmap, totL);
    lr_gather<<<4096, 256, 0, stream>>>((const f32x4*)x, idx, rowmap, totL, (f32x4*)out);
    lr_fill<<<dim3(MAXLEN / 64, BB), 256, 0, stream>>>(ml, (f32x4*)out);
}